// Round 24
// baseline (85.853 us; speedup 1.0000x reference)
//
#include <hip/hip_runtime.h>
#include <math.h>

// Problem constants
constexpr int N = 8, C = 128, H = 64, W = 64;
constexpr int PIX = H * W;            // 4096
constexpr int KK = 49;                // 7x7 window

// ws layout (floats) — first 32768 floats hold 4 bf16 A-matrices (hi/lo x 2)
constexpr size_t Z_OFF   = 65536;                    // z = M^T x
constexpr size_t YSZ     = (size_t)N * C * PIX;      // 4,194,304
constexpr size_t SIM_OFF = Z_OFF + YSZ;              // simp fp32 x2 [g][49][256]
constexpr size_t SIMSZ   = (size_t)N * 16 * KK * 256;// 1,605,632
constexpr size_t U_OFF   = SIM_OFF + 2 * SIMSZ;      // u = PV(x)
constexpr size_t ATT_OFF = U_OFF + YSZ;              // attn bf16 (as float offset)
constexpr size_t SINV_OFF= ATT_OFF + SIMSZ / 2 + 64; // 1/S fp32 [g][256]

constexpr int SLW = 76;   // stage row width
constexpr int SBW = 76;   // bf16 stage row width in ushorts
constexpr int ALW = 136;  // convm LDS row stride (ushorts)

typedef __attribute__((ext_vector_type(8))) short bf16x8;
typedef __attribute__((ext_vector_type(4))) float f32x4;

__device__ __forceinline__ unsigned bf16rne(float f) {
    unsigned u = __float_as_uint(f);
    u += 0x7FFFu + ((u >> 16) & 1u);
    return u >> 16;
}
__device__ __forceinline__ unsigned packbf(float a, float b) {
    return bf16rne(a) | (bf16rne(b) << 16);
}
__device__ __forceinline__ float bflo(unsigned u) { return __uint_as_float(u << 16); }
__device__ __forceinline__ float bfhi(unsigned u) { return __uint_as_float(u & 0xFFFF0000u); }

// ---------------------------------------------------------------------------
// K0: prep — M = W1^T W2 -> A1 hi/lo bf16; W3 -> A2 hi/lo bf16.  (r15)
// ---------------------------------------------------------------------------
__global__ __launch_bounds__(256) void prep(const float* __restrict__ w1,
                                            const float* __restrict__ w2,
                                            const float* __restrict__ w3,
                                            unsigned short* __restrict__ A1hi,
                                            unsigned short* __restrict__ A1lo,
                                            unsigned short* __restrict__ A2hi,
                                            unsigned short* __restrict__ A2lo) {
    int bid = blockIdx.x, tid = threadIdx.x;
    if (bid < 64) {
        int a = bid * 2 + (tid >> 7);
        int b = tid & 127;
        float s = 0.f;
        for (int c = 0; c < 128; c++)
            s = fmaf(w1[c * 128 + a], w2[c * 128 + b], s);
        unsigned h = bf16rne(s);
        float lo = s - __uint_as_float(h << 16);
        A1hi[b * 128 + a] = (unsigned short)h;
        A1lo[b * 128 + a] = (unsigned short)bf16rne(lo);
    } else {
        int base = (bid - 64) * 4096;
        for (int i = tid; i < 4096; i += 256) {
            int idx = base + i;
            float v = w3[idx];
            unsigned h = bf16rne(v);
            float lo = v - __uint_as_float(h << 16);
            A2hi[idx] = (unsigned short)h;
            A2lo[idx] = (unsigned short)bf16rne(lo);
        }
    }
}

// ---------------------------------------------------------------------------
// K1: split-precision MFMA 1x1-conv (r15, measured-good, unchanged).
// ---------------------------------------------------------------------------
__global__ __launch_bounds__(256) void convm(const unsigned short* __restrict__ Ahi,
                                             const unsigned short* __restrict__ Alo,
                                             const float* __restrict__ Bsrc,
                                             float* __restrict__ Yout) {
    __shared__ __align__(16) unsigned short xh[64 * ALW];
    __shared__ __align__(16) unsigned short xl[64 * ALW];

    int bid = blockIdx.x;
    int pt  = bid & 63;
    int n   = bid >> 6;
    int p0  = pt * 64;

    const float* B = Bsrc + (size_t)n * C * PIX;
    float*       Y = Yout + (size_t)n * C * PIX;

    int tid  = threadIdx.x;
    int wid  = tid >> 6;
    int lane = tid & 63;
    int l15  = lane & 15;
    int lg   = lane >> 4;

    unsigned* xhd = (unsigned*)xh;
    unsigned* xld = (unsigned*)xl;
#pragma unroll
    for (int i = 0; i < 4; i++) {
        int q  = tid + i * 256;
        int cp = q >> 4;
        int f  = q & 15;
        float4 va = *(const float4*)&B[(size_t)(2 * cp) * PIX + p0 + f * 4];
        float4 vb = *(const float4*)&B[(size_t)(2 * cp + 1) * PIX + p0 + f * 4];
        const float* pa = (const float*)&va;
        const float* pb = (const float*)&vb;
#pragma unroll
        for (int j = 0; j < 4; j++) {
            unsigned ha = bf16rne(pa[j]);
            unsigned hb = bf16rne(pb[j]);
            float la = pa[j] - __uint_as_float(ha << 16);
            float lb = pb[j] - __uint_as_float(hb << 16);
            xhd[(f * 4 + j) * 68 + cp] = ha | (hb << 16);
            xld[(f * 4 + j) * 68 + cp] = bf16rne(la) | (bf16rne(lb) << 16);
        }
    }
    __syncthreads();

    f32x4 acc[2][4];
#pragma unroll
    for (int t = 0; t < 2; t++)
#pragma unroll
        for (int p = 0; p < 4; p++) acc[t][p] = (f32x4){0.f, 0.f, 0.f, 0.f};

#pragma unroll
    for (int kc = 0; kc < 4; kc++) {
        int k0 = kc * 32 + lg * 8;
        bf16x8 ah[2], al_[2], bh[4], bl[4];
#pragma unroll
        for (int t = 0; t < 2; t++) {
            int row = wid * 32 + t * 16 + l15;
            ah[t]  = *(const bf16x8*)&Ahi[row * 128 + k0];
            al_[t] = *(const bf16x8*)&Alo[row * 128 + k0];
        }
#pragma unroll
        for (int p = 0; p < 4; p++) {
            bh[p] = *(const bf16x8*)&xh[(p * 16 + l15) * ALW + k0];
            bl[p] = *(const bf16x8*)&xl[(p * 16 + l15) * ALW + k0];
        }
#pragma unroll
        for (int t = 0; t < 2; t++)
#pragma unroll
            for (int p = 0; p < 4; p++) {
                acc[t][p] = __builtin_amdgcn_mfma_f32_16x16x32_bf16(
                    ah[t], bh[p], acc[t][p], 0, 0, 0);
                acc[t][p] = __builtin_amdgcn_mfma_f32_16x16x32_bf16(
                    ah[t], bl[p], acc[t][p], 0, 0, 0);
                acc[t][p] = __builtin_amdgcn_mfma_f32_16x16x32_bf16(
                    al_[t], bh[p], acc[t][p], 0, 0, 0);
            }
    }

#pragma unroll
    for (int t = 0; t < 2; t++) {
#pragma unroll
        for (int p = 0; p < 4; p++) {
#pragma unroll
            for (int reg = 0; reg < 4; reg++) {
                int oc = wid * 32 + t * 16 + lg * 4 + reg;
                int px = p0 + p * 16 + l15;
                Y[(size_t)oc * PIX + px] = acc[t][p][reg];
            }
        }
    }
}

// ---------------------------------------------------------------------------
// K2: simk11 — simk10 with WHOLE 64-channel bf16 tile staged up-front:
// 16 f4 global loads/thread in one burst (16-deep MLP), pack, ONE barrier,
// straight 64-channel compute, barrier, reduce.  Barriers 9 -> 3.
// Identical arithmetic order to simk10 (bit-identical result).
// LDS: stage 64c*4r*76 ush = 38,912 B >= reduce 5376 f (21.5 KB), aliased.
// ---------------------------------------------------------------------------
__global__ __launch_bounds__(256) void simk11(const float* __restrict__ z,
                                              const float* __restrict__ x,
                                              float* __restrict__ simp) {
    __shared__ __align__(16) float st[9728];      // 38,912 B
    unsigned short* stb = (unsigned short*)st;

    int bid = blockIdx.x;
    int t7  = bid >> 7;          // 0..13
    int di  = t7 % 7;
    int chalf = t7 / 7;
    int g   = bid & 127;
    int n   = g >> 4;
    int hq  = g & 15;
    int h0  = hq * 4;
    int cbase = chalf * 64;

    int tid  = threadIdx.x;
    int wid  = tid >> 6;
    int lane = tid & 63;
    int r = lane >> 4, w4 = lane & 15, wpx = w4 * 4;
    int qw = tid & 15, qc = (tid >> 4) & 15;   // staging: c = qc + 16*phase

    const float* zb = z + (size_t)n * C * PIX;
    const float* xb = x + (size_t)n * C * PIX;
    float* simb = simp + (size_t)chalf * SIMSZ + ((size_t)g * KK) * 256;

    int hh0 = h0 + di - 3;

    // halo zero (64 c x 4 rows x 8 halo cols)
    for (int idx = tid; idx < 64 * 4 * 8; idx += 256) {
        int col8 = idx & 7;
        int row  = (idx >> 3) & 3;
        int c    = idx >> 5;
        int col  = (col8 < 4) ? col8 : 64 + col8;
        stb[(c * 4 + row) * SBW + col] = 0;
    }

    // z loads (16 floats/lane) — issued early, used in compute
    float4 zs[4];
#pragma unroll
    for (int c = 0; c < 4; c++)
        zs[c] = *(const float4*)&zb[(size_t)(cbase + wid * 4 + c) * PIX
                                    + (h0 + r) * 64 + wpx];

    // stage ALL 64 channels: 4 phases x 4 rows = 16 f4 loads/thread
#pragma unroll
    for (int ph = 0; ph < 4; ph++) {
        int c = ph * 16 + qc;
        float4 v[4];
#pragma unroll
        for (int i = 0; i < 4; i++) {
            int hh = hh0 + i;
            float4 t = make_float4(0.f, 0.f, 0.f, 0.f);
            if ((unsigned)hh < 64u)
                t = *(const float4*)&xb[(size_t)(cbase + c) * PIX + hh * 64 + qw * 4];
            v[i] = t;
        }
#pragma unroll
        for (int i = 0; i < 4; i++) {
            uint2 p;
            p.x = packbf(v[i].x, v[i].y);
            p.y = packbf(v[i].z, v[i].w);
            *(uint2*)&stb[(c * 4 + i) * SBW + 4 + qw * 4] = p;
        }
    }
    __syncthreads();   // full tile staged

    float acc[7][4];
#pragma unroll
    for (int dj = 0; dj < 7; dj++)
#pragma unroll
        for (int j = 0; j < 4; j++) acc[dj][j] = 0.f;

    // compute: wave's 4-channel group per 16-chunk, chunks ascending
    // (same c order as simk10: c = ch*16 + wid*4 + cc)
#pragma unroll
    for (int ch = 0; ch < 4; ch++) {
        float4 z4;
        // reload z for chunks > 0 (same address pattern as simk10's zs pipeline)
        if (ch > 0) {
#pragma unroll
            for (int c = 0; c < 4; c++)
                zs[c] = *(const float4*)&zb[(size_t)(cbase + ch * 16 + wid * 4 + c) * PIX
                                            + (h0 + r) * 64 + wpx];
        }
#pragma unroll
        for (int c = 0; c < 4; c++) {
            int cl = ch * 16 + wid * 4 + c;
            const unsigned short* rp = &stb[(cl * 4 + r) * SBW + wpx];
            uint2 q0 = *(const uint2*)&rp[0];
            uint2 q1 = *(const uint2*)&rp[4];
            uint2 q2 = *(const uint2*)&rp[8];
            float rw[12];
            rw[0]  = bflo(q0.x); rw[1]  = bfhi(q0.x);
            rw[2]  = bflo(q0.y); rw[3]  = bfhi(q0.y);
            rw[4]  = bflo(q1.x); rw[5]  = bfhi(q1.x);
            rw[6]  = bflo(q1.y); rw[7]  = bfhi(q1.y);
            rw[8]  = bflo(q2.x); rw[9]  = bfhi(q2.x);
            rw[10] = bflo(q2.y); rw[11] = bfhi(q2.y);
            const float* zp = (const float*)&zs[c];
#pragma unroll
            for (int dj = 0; dj < 7; dj++)
#pragma unroll
                for (int j = 0; j < 4; j++)
                    acc[dj][j] = fmaf(zp[j], rw[j + dj + 1], acc[dj][j]);
        }
    }
    __syncthreads();   // compute done; st reusable as reduce buffer

    // cross-wave reduce
    if (wid > 0) {
#pragma unroll
        for (int dj = 0; dj < 7; dj++) {
            float4 v = make_float4(acc[dj][0], acc[dj][1], acc[dj][2], acc[dj][3]);
            *(float4*)&st[((wid - 1) * 7 + dj) * 256 + lane * 4] = v;
        }
    }
    __syncthreads();
    if (wid == 0) {
#pragma unroll
        for (int s = 0; s < 3; s++)
#pragma unroll
            for (int dj = 0; dj < 7; dj++) {
                float4 v = *(const float4*)&st[(s * 7 + dj) * 256 + lane * 4];
                acc[dj][0] += v.x; acc[dj][1] += v.y;
                acc[dj][2] += v.z; acc[dj][3] += v.w;
            }
#pragma unroll
        for (int dj = 0; dj < 7; dj++) {
            int k = di * 7 + dj;
            float4 v = make_float4(acc[dj][0], acc[dj][1], acc[dj][2], acc[dj][3]);
            *(float4*)&simb[(size_t)k * 256 + r * 64 + wpx] = v;
        }
    }
}

// ---------------------------------------------------------------------------
// K2.5: softk3 — softmax ONCE per g (r22, measured-good, unchanged).
// ---------------------------------------------------------------------------
__global__ __launch_bounds__(256) void softk3(const float* __restrict__ simp,
                                              unsigned short* __restrict__ attn_g,
                                              float* __restrict__ sinvg) {
    int g  = blockIdx.x;
    int px = threadIdx.x;
    const float* simb  = simp + (size_t)g * KK * 256;
    const float* simb2 = simb + SIMSZ;
    unsigned short* ab = attn_g + (size_t)g * KK * 256;

    float sv[KK];
    float m = -1e30f;
#pragma unroll
    for (int k = 0; k < KK; k++) {
        size_t off = (size_t)k * 256 + px;
        sv[k] = simb[off] + simb2[off];
        m = fmaxf(m, sv[k]);
    }
    float s = 0.f;
#pragma unroll
    for (int k = 0; k < KK; k++) {
        float e = __expf(sv[k] - m);
        s += e;
        ab[(size_t)k * 256 + px] = (unsigned short)bf16rne(e);
    }
    sinvg[g * 256 + px] = 1.f / s;
}

// ---------------------------------------------------------------------------
// K3: softpv12 — PV only (r22, measured-good, unchanged).
// ---------------------------------------------------------------------------
__global__ __launch_bounds__(512) void softpv12(const unsigned short* __restrict__ attn_g,
                                                const float* __restrict__ sinvg,
                                                const float* __restrict__ x,
                                                float* __restrict__ u) {
    __shared__ __align__(16) unsigned short stb[16 * 10 * SBW];  // 24,320 B
    __shared__ __align__(16) unsigned short al[KK * 256];        // 25,088 B

    int bid = blockIdx.x;
    int cqb = bid >> 7;
    int g   = bid & 127;
    int n   = g >> 4;
    int hq  = g & 15;
    int h0  = hq * 4;

    int tid  = threadIdx.x;
    int wid  = tid >> 6;
    int lane = tid & 63;
    int r = lane >> 4, w4 = lane & 15, wpx = w4 * 4;

    const unsigned short* ag = attn_g + (size_t)g * KK * 256;
    const float* sg = sinvg + g * 256;
    const float* xb = x + (size_t)n * C * PIX;
    float* ub = u + (size_t)n * C * PIX;

    int sqw[5], sqc[5], sqr[5];
#pragma unroll
    for (int i = 0; i < 5; i++) {
        int q  = tid + i * 512;
        sqw[i] = q & 15; sqc[i] = (q >> 4) & 15; sqr[i] = q >> 8;
    }

    float4 xs[5];
    {
        int c0 = cqb * 32;
#pragma unroll
        for (int i = 0; i < 5; i++) {
            int hh = h0 - 3 + sqr[i];
            float4 v = make_float4(0.f, 0.f, 0.f, 0.f);
            if ((unsigned)hh < 64u)
                v = *(const float4*)&xb[(size_t)(c0 + sqc[i]) * PIX + hh * 64 + sqw[i] * 4];
            xs[i] = v;
        }
    }

    {
        const uint4* src = (const uint4*)ag;
        uint4* dst = (uint4*)al;
        for (int q = tid; q < 1568; q += 512) dst[q] = src[q];
    }
    for (int idx = tid; idx < 16 * 10 * 12; idx += 512) {
        int i12  = idx % 12;
        int rowc = idx / 12;
        int col  = (i12 < 4) ? i12 : 64 + i12;
        stb[rowc * SBW + col] = 0;
    }

#pragma unroll
    for (int i = 0; i < 5; i++) {
        uint2 p;
        p.x = packbf(xs[i].x, xs[i].y);
        p.y = packbf(xs[i].z, xs[i].w);
        *(uint2*)&stb[(sqc[i] * 10 + sqr[i]) * SBW + 4 + sqw[i] * 4] = p;
    }
    {
        int c1 = cqb * 32 + 16;
#pragma unroll
        for (int i = 0; i < 5; i++) {
            int hh = h0 - 3 + sqr[i];
            float4 v = make_float4(0.f, 0.f, 0.f, 0.f);
            if ((unsigned)hh < 64u)
                v = *(const float4*)&xb[(size_t)(c1 + sqc[i]) * PIX + hh * 64 + sqw[i] * 4];
            xs[i] = v;
        }
    }
    __syncthreads();

    float4 s4 = *(const float4*)&sg[r * 64 + wpx];
    const float* sp = (const float*)&s4;

    int cw = wid * 2;
#pragma unroll
    for (int ch2 = 0; ch2 < 2; ch2++) {
        int c0 = cqb * 32 + ch2 * 16;
        float u4[2][4];
#pragma unroll
        for (int cl = 0; cl < 2; cl++)
#pragma unroll
            for (int j = 0; j < 4; j++) u4[cl][j] = 0.f;

        for (int di = 0; di < 7; di++) {
#pragma unroll
            for (int cl = 0; cl < 2; cl++) {
                const unsigned short* rp = &stb[((cw + cl) * 10 + r + di) * SBW + wpx];
                uint2 q0 = *(const uint2*)&rp[0];
                uint2 q1 = *(const uint2*)&rp[4];
                uint2 q2 = *(const uint2*)&rp[8];
                float rw[12];
                rw[0]  = bflo(q0.x); rw[1]  = bfhi(q0.x);
                rw[2]  = bflo(q0.y); rw[3]  = bfhi(q0.y);
                rw[4]  = bflo(q1.x); rw[5]  = bfhi(q1.x);
                rw[6]  = bflo(q1.y); rw[7]  = bfhi(q1.y);
                rw[8]  = bflo(q2.x); rw[9]  = bfhi(q2.x);
                rw[10] = bflo(q2.y); rw[11] = bfhi(q2.y);
#pragma unroll
                for (int dj = 0; dj < 7; dj++) {
                    uint2 p = *(const uint2*)&al[(di * 7 + dj) * 256 + r * 64 + wpx];
                    float a0 = bflo(p.x), a1 = bfhi(p.x);
                    float a2 = bflo(p.y), a3 = bfhi(p.y);
                    u4[cl][0] = fmaf(a0, rw[dj + 1], u4[cl][0]);
                    u4[cl][1] = fmaf(a1, rw[dj + 2], u4[cl][1]);
                    u4[cl][2] = fmaf(a2, rw[dj + 3], u4[cl][2]);
                    u4[cl][3] = fmaf(a3, rw[dj + 4], u4[cl][3]);
                }
            }
        }

#pragma unroll
        for (int cl = 0; cl < 2; cl++) {
            int c = c0 + cw + cl;
            float4 v = make_float4(u4[cl][0] * sp[0], u4[cl][1] * sp[1],
                                   u4[cl][2] * sp[2], u4[cl][3] * sp[3]);
            *(float4*)&ub[(size_t)c * PIX + (h0 + r) * 64 + wpx] = v;
        }

        if (ch2 == 0) {
            __syncthreads();
#pragma unroll
            for (int i = 0; i < 5; i++) {
                uint2 p;
                p.x = packbf(xs[i].x, xs[i].y);
                p.y = packbf(xs[i].z, xs[i].w);
                *(uint2*)&stb[(sqc[i] * 10 + sqr[i]) * SBW + 4 + sqw[i] * 4] = p;
            }
            __syncthreads();
        }
    }
}

// ---------------------------------------------------------------------------
extern "C" void kernel_launch(void* const* d_in, const int* in_sizes, int n_in,
                              void* d_out, int out_size, void* d_ws, size_t ws_size,
                              hipStream_t stream) {
    const float* x  = (const float*)d_in[0];
    const float* w1 = (const float*)d_in[1];
    const float* w2 = (const float*)d_in[2];
    const float* w3 = (const float*)d_in[3];
    float* wsf = (float*)d_ws;
    unsigned short* A1hi = (unsigned short*)wsf;
    unsigned short* A1lo = A1hi + 16384;
    unsigned short* A2hi = A1hi + 32768;
    unsigned short* A2lo = A1hi + 49152;
    unsigned short* attn_g = (unsigned short*)(wsf + ATT_OFF);
    float* sinvg = wsf + SINV_OFF;

    prep<<<68, 256, 0, stream>>>(w1, w2, w3, A1hi, A1lo, A2hi, A2lo);
    convm<<<512, 256, 0, stream>>>(A1hi, A1lo, x, wsf + Z_OFF);             // z
    simk11<<<1792, 256, 0, stream>>>(wsf + Z_OFF, x, wsf + SIM_OFF);        // partial sims
    softk3<<<128, 256, 0, stream>>>(wsf + SIM_OFF, attn_g, sinvg);          // softmax once
    softpv12<<<512, 512, 0, stream>>>(attn_g, sinvg, x, wsf + U_OFF);       // PV
    convm<<<512, 256, 0, stream>>>(A2hi, A2lo, wsf + U_OFF, (float*)d_out); // out
}

// Round 25
// 81.577 us; speedup vs baseline: 1.0524x; 1.0524x over previous
//
#include <hip/hip_runtime.h>
#include <math.h>

// Problem constants
constexpr int N = 8, C = 128, H = 64, W = 64;
constexpr int PIX = H * W;            // 4096
constexpr int KK = 49;                // 7x7 window

// ws layout (floats) — first 32768 floats hold 4 bf16 A-matrices (hi/lo x 2)
constexpr size_t Z_OFF   = 65536;                    // z = M^T x
constexpr size_t YSZ     = (size_t)N * C * PIX;      // 4,194,304
constexpr size_t SIM_OFF = Z_OFF + YSZ;              // simp fp32 x2 [g][49][256]
constexpr size_t SIMSZ   = (size_t)N * 16 * KK * 256;// 1,605,632
constexpr size_t U_OFF   = SIM_OFF + 2 * SIMSZ;      // u = PV(x)
constexpr size_t ATT_OFF = U_OFF + YSZ;              // attn bf16 (as float offset)
constexpr size_t SINV_OFF= ATT_OFF + SIMSZ / 2 + 64; // 1/S fp32 [g][256]

constexpr int SLW = 76;   // stage row width
constexpr int SBW = 76;   // bf16 stage row width in ushorts
constexpr int ALW = 136;  // convm LDS row stride (ushorts)

typedef __attribute__((ext_vector_type(8))) short bf16x8;
typedef __attribute__((ext_vector_type(4))) float f32x4;

__device__ __forceinline__ unsigned bf16rne(float f) {
    unsigned u = __float_as_uint(f);
    u += 0x7FFFu + ((u >> 16) & 1u);
    return u >> 16;
}
__device__ __forceinline__ unsigned packbf(float a, float b) {
    return bf16rne(a) | (bf16rne(b) << 16);
}
__device__ __forceinline__ float bflo(unsigned u) { return __uint_as_float(u << 16); }
__device__ __forceinline__ float bfhi(unsigned u) { return __uint_as_float(u & 0xFFFF0000u); }

// ---------------------------------------------------------------------------
// K0: prep — M = W1^T W2 -> A1 hi/lo bf16; W3 -> A2 hi/lo bf16.  (r15)
// ---------------------------------------------------------------------------
__global__ __launch_bounds__(256) void prep(const float* __restrict__ w1,
                                            const float* __restrict__ w2,
                                            const float* __restrict__ w3,
                                            unsigned short* __restrict__ A1hi,
                                            unsigned short* __restrict__ A1lo,
                                            unsigned short* __restrict__ A2hi,
                                            unsigned short* __restrict__ A2lo) {
    int bid = blockIdx.x, tid = threadIdx.x;
    if (bid < 64) {
        int a = bid * 2 + (tid >> 7);
        int b = tid & 127;
        float s = 0.f;
        for (int c = 0; c < 128; c++)
            s = fmaf(w1[c * 128 + a], w2[c * 128 + b], s);
        unsigned h = bf16rne(s);
        float lo = s - __uint_as_float(h << 16);
        A1hi[b * 128 + a] = (unsigned short)h;
        A1lo[b * 128 + a] = (unsigned short)bf16rne(lo);
    } else {
        int base = (bid - 64) * 4096;
        for (int i = tid; i < 4096; i += 256) {
            int idx = base + i;
            float v = w3[idx];
            unsigned h = bf16rne(v);
            float lo = v - __uint_as_float(h << 16);
            A2hi[idx] = (unsigned short)h;
            A2lo[idx] = (unsigned short)bf16rne(lo);
        }
    }
}

// ---------------------------------------------------------------------------
// K1: split-precision MFMA 1x1-conv (r15, measured-good, unchanged).
// ---------------------------------------------------------------------------
__global__ __launch_bounds__(256) void convm(const unsigned short* __restrict__ Ahi,
                                             const unsigned short* __restrict__ Alo,
                                             const float* __restrict__ Bsrc,
                                             float* __restrict__ Yout) {
    __shared__ __align__(16) unsigned short xh[64 * ALW];
    __shared__ __align__(16) unsigned short xl[64 * ALW];

    int bid = blockIdx.x;
    int pt  = bid & 63;
    int n   = bid >> 6;
    int p0  = pt * 64;

    const float* B = Bsrc + (size_t)n * C * PIX;
    float*       Y = Yout + (size_t)n * C * PIX;

    int tid  = threadIdx.x;
    int wid  = tid >> 6;
    int lane = tid & 63;
    int l15  = lane & 15;
    int lg   = lane >> 4;

    unsigned* xhd = (unsigned*)xh;
    unsigned* xld = (unsigned*)xl;
#pragma unroll
    for (int i = 0; i < 4; i++) {
        int q  = tid + i * 256;
        int cp = q >> 4;
        int f  = q & 15;
        float4 va = *(const float4*)&B[(size_t)(2 * cp) * PIX + p0 + f * 4];
        float4 vb = *(const float4*)&B[(size_t)(2 * cp + 1) * PIX + p0 + f * 4];
        const float* pa = (const float*)&va;
        const float* pb = (const float*)&vb;
#pragma unroll
        for (int j = 0; j < 4; j++) {
            unsigned ha = bf16rne(pa[j]);
            unsigned hb = bf16rne(pb[j]);
            float la = pa[j] - __uint_as_float(ha << 16);
            float lb = pb[j] - __uint_as_float(hb << 16);
            xhd[(f * 4 + j) * 68 + cp] = ha | (hb << 16);
            xld[(f * 4 + j) * 68 + cp] = bf16rne(la) | (bf16rne(lb) << 16);
        }
    }
    __syncthreads();

    f32x4 acc[2][4];
#pragma unroll
    for (int t = 0; t < 2; t++)
#pragma unroll
        for (int p = 0; p < 4; p++) acc[t][p] = (f32x4){0.f, 0.f, 0.f, 0.f};

#pragma unroll
    for (int kc = 0; kc < 4; kc++) {
        int k0 = kc * 32 + lg * 8;
        bf16x8 ah[2], al_[2], bh[4], bl[4];
#pragma unroll
        for (int t = 0; t < 2; t++) {
            int row = wid * 32 + t * 16 + l15;
            ah[t]  = *(const bf16x8*)&Ahi[row * 128 + k0];
            al_[t] = *(const bf16x8*)&Alo[row * 128 + k0];
        }
#pragma unroll
        for (int p = 0; p < 4; p++) {
            bh[p] = *(const bf16x8*)&xh[(p * 16 + l15) * ALW + k0];
            bl[p] = *(const bf16x8*)&xl[(p * 16 + l15) * ALW + k0];
        }
#pragma unroll
        for (int t = 0; t < 2; t++)
#pragma unroll
            for (int p = 0; p < 4; p++) {
                acc[t][p] = __builtin_amdgcn_mfma_f32_16x16x32_bf16(
                    ah[t], bh[p], acc[t][p], 0, 0, 0);
                acc[t][p] = __builtin_amdgcn_mfma_f32_16x16x32_bf16(
                    ah[t], bl[p], acc[t][p], 0, 0, 0);
                acc[t][p] = __builtin_amdgcn_mfma_f32_16x16x32_bf16(
                    al_[t], bh[p], acc[t][p], 0, 0, 0);
            }
    }

#pragma unroll
    for (int t = 0; t < 2; t++) {
#pragma unroll
        for (int p = 0; p < 4; p++) {
#pragma unroll
            for (int reg = 0; reg < 4; reg++) {
                int oc = wid * 32 + t * 16 + lg * 4 + reg;
                int px = p0 + p * 16 + l15;
                Y[(size_t)oc * PIX + px] = acc[t][p][reg];
            }
        }
    }
}

// ---------------------------------------------------------------------------
// K2: simk10 — channel-half split sim with BF16 window stage (r23, best).
// 4-chunk ping-pong (T14), bf16 pack on store, bflo/bfhi unpack on read.
// ---------------------------------------------------------------------------
__global__ __launch_bounds__(256) void simk10(const float* __restrict__ z,
                                              const float* __restrict__ x,
                                              float* __restrict__ simp) {
    __shared__ __align__(16) float st[5376];
    unsigned short* stb = (unsigned short*)st;

    int bid = blockIdx.x;
    int t7  = bid >> 7;          // 0..13
    int di  = t7 % 7;
    int chalf = t7 / 7;
    int g   = bid & 127;
    int n   = g >> 4;
    int hq  = g & 15;
    int h0  = hq * 4;
    int cbase = chalf * 64;

    int tid  = threadIdx.x;
    int wid  = tid >> 6;
    int lane = tid & 63;
    int r = lane >> 4, w4 = lane & 15, wpx = w4 * 4;
    int qw = tid & 15, qc = (tid >> 4) & 15;

    const float* zb = z + (size_t)n * C * PIX;
    const float* xb = x + (size_t)n * C * PIX;
    float* simb = simp + (size_t)chalf * SIMSZ + ((size_t)g * KK) * 256;

    // halo zero (ushort cols 0..3, 68..75)
    for (int idx = tid; idx < 16 * 4 * 8; idx += 256) {
        int col8 = idx & 7;
        int row  = (idx >> 3) & 3;
        int c    = idx >> 5;
        int col  = (col8 < 4) ? col8 : 64 + col8;
        stb[(c * 4 + row) * SBW + col] = 0;
    }

    float acc[7][4];
#pragma unroll
    for (int dj = 0; dj < 7; dj++)
#pragma unroll
        for (int j = 0; j < 4; j++) acc[dj][j] = 0.f;

    int hh0 = h0 + di - 3;
    float4 xs[2][4], zs[2][4];

#pragma unroll
    for (int i = 0; i < 4; i++) {
        int hh = hh0 + i;
        float4 v = make_float4(0.f, 0.f, 0.f, 0.f);
        if ((unsigned)hh < 64u)
            v = *(const float4*)&xb[(size_t)(cbase + qc) * PIX + hh * 64 + qw * 4];
        xs[0][i] = v;
    }
#pragma unroll
    for (int c = 0; c < 4; c++)
        zs[0][c] = *(const float4*)&zb[(size_t)(cbase + wid * 4 + c) * PIX
                                       + (h0 + r) * 64 + wpx];

#pragma unroll
    for (int ch = 0; ch < 4; ch++) {
        int cur = ch & 1, nxt = cur ^ 1;
        // stage current chunk as bf16
#pragma unroll
        for (int i = 0; i < 4; i++) {
            uint2 p;
            p.x = packbf(xs[cur][i].x, xs[cur][i].y);
            p.y = packbf(xs[cur][i].z, xs[cur][i].w);
            *(uint2*)&stb[(qc * 4 + i) * SBW + 4 + qw * 4] = p;
        }
        if (ch < 3) {
            int cb = cbase + (ch + 1) * 16;
#pragma unroll
            for (int i = 0; i < 4; i++) {
                int hh = hh0 + i;
                float4 v = make_float4(0.f, 0.f, 0.f, 0.f);
                if ((unsigned)hh < 64u)
                    v = *(const float4*)&xb[(size_t)(cb + qc) * PIX + hh * 64 + qw * 4];
                xs[nxt][i] = v;
            }
#pragma unroll
            for (int c = 0; c < 4; c++)
                zs[nxt][c] = *(const float4*)&zb[(size_t)(cb + wid * 4 + c) * PIX
                                                 + (h0 + r) * 64 + wpx];
        }
        __syncthreads();

#pragma unroll
        for (int c = 0; c < 4; c++) {
            int cl = wid * 4 + c;
            const unsigned short* rp = &stb[(cl * 4 + r) * SBW + wpx];
            uint2 q0 = *(const uint2*)&rp[0];
            uint2 q1 = *(const uint2*)&rp[4];
            uint2 q2 = *(const uint2*)&rp[8];
            float rw[12];
            rw[0]  = bflo(q0.x); rw[1]  = bfhi(q0.x);
            rw[2]  = bflo(q0.y); rw[3]  = bfhi(q0.y);
            rw[4]  = bflo(q1.x); rw[5]  = bfhi(q1.x);
            rw[6]  = bflo(q1.y); rw[7]  = bfhi(q1.y);
            rw[8]  = bflo(q2.x); rw[9]  = bfhi(q2.x);
            rw[10] = bflo(q2.y); rw[11] = bfhi(q2.y);
            const float* zp = (const float*)&zs[cur][c];
#pragma unroll
            for (int dj = 0; dj < 7; dj++)
#pragma unroll
                for (int j = 0; j < 4; j++)
                    acc[dj][j] = fmaf(zp[j], rw[j + dj + 1], acc[dj][j]);
        }
        __syncthreads();
    }

    // cross-wave reduce (st floats; stage ushort region dead after barrier)
    if (wid > 0) {
#pragma unroll
        for (int dj = 0; dj < 7; dj++) {
            float4 v = make_float4(acc[dj][0], acc[dj][1], acc[dj][2], acc[dj][3]);
            *(float4*)&st[((wid - 1) * 7 + dj) * 256 + lane * 4] = v;
        }
    }
    __syncthreads();
    if (wid == 0) {
#pragma unroll
        for (int s = 0; s < 3; s++)
#pragma unroll
            for (int dj = 0; dj < 7; dj++) {
                float4 v = *(const float4*)&st[(s * 7 + dj) * 256 + lane * 4];
                acc[dj][0] += v.x; acc[dj][1] += v.y;
                acc[dj][2] += v.z; acc[dj][3] += v.w;
            }
#pragma unroll
        for (int dj = 0; dj < 7; dj++) {
            int k = di * 7 + dj;
            float4 v = make_float4(acc[dj][0], acc[dj][1], acc[dj][2], acc[dj][3]);
            *(float4*)&simb[(size_t)k * 256 + r * 64 + wpx] = v;
        }
    }
}

// ---------------------------------------------------------------------------
// K2.5: softk3 — softmax ONCE per g (r22, measured-good, unchanged).
// ---------------------------------------------------------------------------
__global__ __launch_bounds__(256) void softk3(const float* __restrict__ simp,
                                              unsigned short* __restrict__ attn_g,
                                              float* __restrict__ sinvg) {
    int g  = blockIdx.x;
    int px = threadIdx.x;
    const float* simb  = simp + (size_t)g * KK * 256;
    const float* simb2 = simb + SIMSZ;
    unsigned short* ab = attn_g + (size_t)g * KK * 256;

    float sv[KK];
    float m = -1e30f;
#pragma unroll
    for (int k = 0; k < KK; k++) {
        size_t off = (size_t)k * 256 + px;
        sv[k] = simb[off] + simb2[off];
        m = fmaxf(m, sv[k]);
    }
    float s = 0.f;
#pragma unroll
    for (int k = 0; k < KK; k++) {
        float e = __expf(sv[k] - m);
        s += e;
        ab[(size_t)k * 256 + px] = (unsigned short)bf16rne(e);
    }
    sinvg[g * 256 + px] = 1.f / s;
}

// ---------------------------------------------------------------------------
// K3: softpv12 — PV only (r22, measured-good, unchanged).
// ---------------------------------------------------------------------------
__global__ __launch_bounds__(512) void softpv12(const unsigned short* __restrict__ attn_g,
                                                const float* __restrict__ sinvg,
                                                const float* __restrict__ x,
                                                float* __restrict__ u) {
    __shared__ __align__(16) unsigned short stb[16 * 10 * SBW];  // 24,320 B
    __shared__ __align__(16) unsigned short al[KK * 256];        // 25,088 B

    int bid = blockIdx.x;
    int cqb = bid >> 7;
    int g   = bid & 127;
    int n   = g >> 4;
    int hq  = g & 15;
    int h0  = hq * 4;

    int tid  = threadIdx.x;
    int wid  = tid >> 6;
    int lane = tid & 63;
    int r = lane >> 4, w4 = lane & 15, wpx = w4 * 4;

    const unsigned short* ag = attn_g + (size_t)g * KK * 256;
    const float* sg = sinvg + g * 256;
    const float* xb = x + (size_t)n * C * PIX;
    float* ub = u + (size_t)n * C * PIX;

    int sqw[5], sqc[5], sqr[5];
#pragma unroll
    for (int i = 0; i < 5; i++) {
        int q  = tid + i * 512;
        sqw[i] = q & 15; sqc[i] = (q >> 4) & 15; sqr[i] = q >> 8;
    }

    float4 xs[5];
    {
        int c0 = cqb * 32;
#pragma unroll
        for (int i = 0; i < 5; i++) {
            int hh = h0 - 3 + sqr[i];
            float4 v = make_float4(0.f, 0.f, 0.f, 0.f);
            if ((unsigned)hh < 64u)
                v = *(const float4*)&xb[(size_t)(c0 + sqc[i]) * PIX + hh * 64 + sqw[i] * 4];
            xs[i] = v;
        }
    }

    {
        const uint4* src = (const uint4*)ag;
        uint4* dst = (uint4*)al;
        for (int q = tid; q < 1568; q += 512) dst[q] = src[q];
    }
    for (int idx = tid; idx < 16 * 10 * 12; idx += 512) {
        int i12  = idx % 12;
        int rowc = idx / 12;
        int col  = (i12 < 4) ? i12 : 64 + i12;
        stb[rowc * SBW + col] = 0;
    }

#pragma unroll
    for (int i = 0; i < 5; i++) {
        uint2 p;
        p.x = packbf(xs[i].x, xs[i].y);
        p.y = packbf(xs[i].z, xs[i].w);
        *(uint2*)&stb[(sqc[i] * 10 + sqr[i]) * SBW + 4 + sqw[i] * 4] = p;
    }
    {
        int c1 = cqb * 32 + 16;
#pragma unroll
        for (int i = 0; i < 5; i++) {
            int hh = h0 - 3 + sqr[i];
            float4 v = make_float4(0.f, 0.f, 0.f, 0.f);
            if ((unsigned)hh < 64u)
                v = *(const float4*)&xb[(size_t)(c1 + sqc[i]) * PIX + hh * 64 + sqw[i] * 4];
            xs[i] = v;
        }
    }
    __syncthreads();

    float4 s4 = *(const float4*)&sg[r * 64 + wpx];
    const float* sp = (const float*)&s4;

    int cw = wid * 2;
#pragma unroll
    for (int ch2 = 0; ch2 < 2; ch2++) {
        int c0 = cqb * 32 + ch2 * 16;
        float u4[2][4];
#pragma unroll
        for (int cl = 0; cl < 2; cl++)
#pragma unroll
            for (int j = 0; j < 4; j++) u4[cl][j] = 0.f;

        for (int di = 0; di < 7; di++) {
#pragma unroll
            for (int cl = 0; cl < 2; cl++) {
                const unsigned short* rp = &stb[((cw + cl) * 10 + r + di) * SBW + wpx];
                uint2 q0 = *(const uint2*)&rp[0];
                uint2 q1 = *(const uint2*)&rp[4];
                uint2 q2 = *(const uint2*)&rp[8];
                float rw[12];
                rw[0]  = bflo(q0.x); rw[1]  = bfhi(q0.x);
                rw[2]  = bflo(q0.y); rw[3]  = bfhi(q0.y);
                rw[4]  = bflo(q1.x); rw[5]  = bfhi(q1.x);
                rw[6]  = bflo(q1.y); rw[7]  = bfhi(q1.y);
                rw[8]  = bflo(q2.x); rw[9]  = bfhi(q2.x);
                rw[10] = bflo(q2.y); rw[11] = bfhi(q2.y);
#pragma unroll
                for (int dj = 0; dj < 7; dj++) {
                    uint2 p = *(const uint2*)&al[(di * 7 + dj) * 256 + r * 64 + wpx];
                    float a0 = bflo(p.x), a1 = bfhi(p.x);
                    float a2 = bflo(p.y), a3 = bfhi(p.y);
                    u4[cl][0] = fmaf(a0, rw[dj + 1], u4[cl][0]);
                    u4[cl][1] = fmaf(a1, rw[dj + 2], u4[cl][1]);
                    u4[cl][2] = fmaf(a2, rw[dj + 3], u4[cl][2]);
                    u4[cl][3] = fmaf(a3, rw[dj + 4], u4[cl][3]);
                }
            }
        }

#pragma unroll
        for (int cl = 0; cl < 2; cl++) {
            int c = c0 + cw + cl;
            float4 v = make_float4(u4[cl][0] * sp[0], u4[cl][1] * sp[1],
                                   u4[cl][2] * sp[2], u4[cl][3] * sp[3]);
            *(float4*)&ub[(size_t)c * PIX + (h0 + r) * 64 + wpx] = v;
        }

        if (ch2 == 0) {
            __syncthreads();
#pragma unroll
            for (int i = 0; i < 5; i++) {
                uint2 p;
                p.x = packbf(xs[i].x, xs[i].y);
                p.y = packbf(xs[i].z, xs[i].w);
                *(uint2*)&stb[(sqc[i] * 10 + sqr[i]) * SBW + 4 + sqw[i] * 4] = p;
            }
            __syncthreads();
        }
    }
}

// ---------------------------------------------------------------------------
extern "C" void kernel_launch(void* const* d_in, const int* in_sizes, int n_in,
                              void* d_out, int out_size, void* d_ws, size_t ws_size,
                              hipStream_t stream) {
    const float* x  = (const float*)d_in[0];
    const float* w1 = (const float*)d_in[1];
    const float* w2 = (const float*)d_in[2];
    const float* w3 = (const float*)d_in[3];
    float* wsf = (float*)d_ws;
    unsigned short* A1hi = (unsigned short*)wsf;
    unsigned short* A1lo = A1hi + 16384;
    unsigned short* A2hi = A1hi + 32768;
    unsigned short* A2lo = A1hi + 49152;
    unsigned short* attn_g = (unsigned short*)(wsf + ATT_OFF);
    float* sinvg = wsf + SINV_OFF;

    prep<<<68, 256, 0, stream>>>(w1, w2, w3, A1hi, A1lo, A2hi, A2lo);
    convm<<<512, 256, 0, stream>>>(A1hi, A1lo, x, wsf + Z_OFF);             // z
    simk10<<<1792, 256, 0, stream>>>(wsf + Z_OFF, x, wsf + SIM_OFF);        // partial sims
    softk3<<<128, 256, 0, stream>>>(wsf + SIM_OFF, attn_g, sinvg);          // softmax once
    softpv12<<<512, 512, 0, stream>>>(attn_g, sinvg, x, wsf + U_OFF);       // PV
    convm<<<512, 256, 0, stream>>>(A2hi, A2lo, wsf + U_OFF, (float*)d_out); // out
}